// Round 4
// baseline (334.458 us; speedup 1.0000x reference)
//
#include <hip/hip_runtime.h>
#include <math.h>
#include <stdint.h>

#define S 16
#define C 8
#define N 5000
#define T 100
#define N4 1250   // N / 4 float4 columns

typedef float f32x4 __attribute__((ext_vector_type(4)));

// ---------------- Prep kernel ----------------
// blocks 0..15  : emission log-softmax over nodes (row s = blockIdx.x)
// blocks 16..35 : chain log-softmax over chains (256 nodes per block), stored TRANSPOSED
//                 ws_lcwT[c][n] so the main kernel can read it with coalesced float4s
// block  36     : HMM forward recursion in linear space (single wave, no barriers)
__global__ __launch_bounds__(256) void prep_kernel(const float* __restrict__ u_init,
                                                   const float* __restrict__ u_cw,
                                                   const float* __restrict__ u_e,
                                                   const float* __restrict__ u_T,
                                                   float* __restrict__ ws_le,    // (S,N)
                                                   float* __restrict__ ws_lcwT,  // (C,N)
                                                   float* __restrict__ ws_h,     // (T,S)
                                                   float* __restrict__ out_h) {  // (T,S)
    const int b = blockIdx.x;
    const int tid = threadIdx.x;

    if (b < 16) {
        // ---- emission row log-softmax ----
        const float* row = u_e + b * N;
        __shared__ float red[256];
        float m = -INFINITY;
        for (int n = tid; n < N; n += 256) m = fmaxf(m, row[n]);
        red[tid] = m;
        __syncthreads();
        for (int o = 128; o > 0; o >>= 1) {
            if (tid < o) red[tid] = fmaxf(red[tid], red[tid + o]);
            __syncthreads();
        }
        m = red[0];
        __syncthreads();
        float sum = 0.f;
        for (int n = tid; n < N; n += 256) sum += expf(row[n] - m);
        red[tid] = sum;
        __syncthreads();
        for (int o = 128; o > 0; o >>= 1) {
            if (tid < o) red[tid] += red[tid + o];
            __syncthreads();
        }
        const float lse = m + logf(red[0]);
        for (int n = tid; n < N; n += 256) ws_le[b * N + n] = row[n] - lse;
    } else if (b < 36) {
        // ---- chain log-softmax, transposed store ----
        const int n = (b - 16) * 256 + tid;
        if (n < N) {
            float v[C];
            float m = -INFINITY;
            for (int c = 0; c < C; ++c) {
                v[c] = u_cw[n * C + c];
                m = fmaxf(m, v[c]);
            }
            float s = 0.f;
            for (int c = 0; c < C; ++c) s += expf(v[c] - m);
            const float lse = m + logf(s);
            for (int c = 0; c < C; ++c) ws_lcwT[c * N + n] = v[c] - lse;
        }
    } else {
        // ---- HMM forward recursion, linear space, single wave ----
        if (tid < S) {
            const int j = tid;
            // log-softmax of state init
            float m = -INFINITY;
            for (int i = 0; i < S; ++i) m = fmaxf(m, u_init[i]);
            float ssum = 0.f;
            for (int i = 0; i < S; ++i) ssum += expf(u_init[i] - m);
            const float lse0 = m + logf(ssum);
            const float h0 = u_init[j] - lse0;
            out_h[j] = h0;
            ws_h[j] = h0;
            // row-softmax of transition: thread j computes lse of row j
            float mr = -INFINITY;
            for (int k = 0; k < S; ++k) mr = fmaxf(mr, u_T[j * S + k]);
            float sr = 0.f;
            for (int k = 0; k < S; ++k) sr += expf(u_T[j * S + k] - mr);
            const float lse_row = mr + logf(sr);
            // thread j holds column j of Texp: Texp[i][j] = exp(u_T[i][j] - lse_i)
            float texp[S];
            #pragma unroll
            for (int i = 0; i < S; ++i) {
                const float lse_i = __shfl(lse_row, i, 64);
                texp[i] = expf(u_T[i * S + j] - lse_i);
            }
            // p_{t+1}[j] = sum_i p_t[i] * Texp[i][j]; h_t = log(p_t)
            float p = expf(h0);
            for (int t = 1; t < T; ++t) {
                float pn = 0.f;
                #pragma unroll
                for (int i = 0; i < S; ++i) {
                    pn = fmaf(__shfl(p, i, 64), texp[i], pn);
                }
                p = pn;
                const float hv = logf(p);
                out_h[t * S + j] = hv;
                ws_h[t * S + j] = hv;
            }
        }
    }
}

// ---------------- Main fused kernel ----------------
// grid (S+1, T).
// bx < 16 : block (s=bx, t) writes the CONTIGUOUS 160 KB slab out_perm[t][s][:][:]
//           in linear address order (c outer, n inner):
//             out_perm[t][s][c][n] = le[s][n] + h[t][s] + lcwT[c][n]
// bx == 16: logsumexp over s for row t:
//             out0[t][n] = log(sum_s exp(le[s][n] + h[t][s]))
//           (exact without max subtraction: all terms <= 0, |a| ~< 25, no overflow
//            possible and exp stays in normal range)
__global__ __launch_bounds__(256) void main_kernel(const float* __restrict__ ws_le,
                                                   const float* __restrict__ ws_lcwT,
                                                   const float* __restrict__ ws_h,
                                                   float* __restrict__ out0,
                                                   float* __restrict__ out_perm) {
    const int t = blockIdx.y;
    const int bx = blockIdx.x;
    const int tid = threadIdx.x;

    if (bx < S) {
        const int s = bx;
        const float hs = ws_h[t * S + s];   // wave-uniform scalar load
        const f32x4* __restrict__ le4 = (const f32x4*)ws_le + s * N4;
        const f32x4* __restrict__ lc4 = (const f32x4*)ws_lcwT;
        f32x4* __restrict__ out4 = (f32x4*)out_perm + (size_t)(t * S + s) * (C * N4);

        for (int c = 0; c < C; ++c) {
            for (int base = 0; base < N4; base += 256) {
                const int n4 = base + tid;
                if (n4 < N4) {
                    const f32x4 e = le4[n4];
                    const f32x4 w = lc4[c * N4 + n4];
                    f32x4 r;
                    r.x = e.x + hs + w.x;
                    r.y = e.y + hs + w.y;
                    r.z = e.z + hs + w.z;
                    r.w = e.w + hs + w.w;
                    out4[c * N4 + n4] = r;
                }
            }
        }
    } else {
        __shared__ float h[S];
        if (tid < S) h[tid] = ws_h[t * S + tid];
        __syncthreads();
        const f32x4* __restrict__ le4 = (const f32x4*)ws_le;
        for (int base = 0; base < N4; base += 256) {
            const int n4 = base + tid;
            if (n4 < N4) {
                float sx = 0.f, sy = 0.f, sz = 0.f, sw = 0.f;
                #pragma unroll
                for (int s = 0; s < S; ++s) {
                    const f32x4 e = le4[s * N4 + n4];
                    const float hv = h[s];
                    sx += expf(e.x + hv);
                    sy += expf(e.y + hv);
                    sz += expf(e.z + hv);
                    sw += expf(e.w + hv);
                }
                f32x4 r;
                r.x = logf(sx);
                r.y = logf(sy);
                r.z = logf(sz);
                r.w = logf(sw);
                ((f32x4*)out0)[(size_t)t * N4 + n4] = r;
            }
        }
    }
}

extern "C" void kernel_launch(void* const* d_in, const int* in_sizes, int n_in,
                              void* d_out, int out_size, void* d_ws, size_t ws_size,
                              hipStream_t stream) {
    const float* u_init = (const float*)d_in[0];   // (S,)
    const float* u_cw   = (const float*)d_in[1];   // (1,N,C)
    const float* u_e    = (const float*)d_in[2];   // (S,N)
    const float* u_T    = (const float*)d_in[3];   // (S,S)

    float* out = (float*)d_out;
    float* out0     = out;                                          // (T,N)
    float* out_perm = out + (size_t)T * N;                          // (T,S,C,N)
    float* out_h    = out + (size_t)T * N + (size_t)T * S * C * N;  // (T,S)

    float* ws  = (float*)d_ws;
    float* ws_h    = ws;                   // 1600 floats
    float* ws_le   = ws + 1600;            // 80000 floats (offset 6400 B, 16B-aligned)
    float* ws_lcwT = ws + 1600 + 80000;    // 40000 floats (C,N transposed)

    prep_kernel<<<37, 256, 0, stream>>>(u_init, u_cw, u_e, u_T, ws_le, ws_lcwT, ws_h, out_h);

    // MEASUREMENT ROUND: launch main twice. The second launch rewrites identical
    // values (deterministic), so correctness is unchanged. dur_us(this) - 286.2
    // = true marginal duration of one main_kernel dispatch, which the top-5
    // counter view cannot show (it is hidden below the ~157 us poison fills).
    // Decision rule: delta ~40-75 us -> main is at the streaming-write roofline
    // and the rest of the 286 us is harness fill/overhead (declare roofline);
    // delta ~105-135 us -> main runs at ~2 TB/s and the write path has real
    // headroom to attack.
    main_kernel<<<dim3(S + 1, T), 256, 0, stream>>>(ws_le, ws_lcwT, ws_h, out0, out_perm);
    main_kernel<<<dim3(S + 1, T), 256, 0, stream>>>(ws_le, ws_lcwT, ws_h, out0, out_perm);
}

// Round 5
// 286.095 us; speedup vs baseline: 1.1690x; 1.1690x over previous
//
#include <hip/hip_runtime.h>
#include <math.h>
#include <stdint.h>

#define S 16
#define C 8
#define N 5000
#define T 100
#define N4 1250   // N / 4 float4 columns

typedef float f32x4 __attribute__((ext_vector_type(4)));

// ---------------- Prep kernel ----------------
// blocks 0..15  : emission log-softmax over nodes (row s = blockIdx.x)
// blocks 16..35 : chain log-softmax over chains (256 nodes per block), stored TRANSPOSED
//                 ws_lcwT[c][n] so the main kernel can read it with coalesced float4s
// block  36     : HMM forward recursion in linear space (single wave, no barriers)
__global__ __launch_bounds__(256) void prep_kernel(const float* __restrict__ u_init,
                                                   const float* __restrict__ u_cw,
                                                   const float* __restrict__ u_e,
                                                   const float* __restrict__ u_T,
                                                   float* __restrict__ ws_le,    // (S,N)
                                                   float* __restrict__ ws_lcwT,  // (C,N)
                                                   float* __restrict__ ws_h,     // (T,S)
                                                   float* __restrict__ out_h) {  // (T,S)
    const int b = blockIdx.x;
    const int tid = threadIdx.x;

    if (b < 16) {
        // ---- emission row log-softmax ----
        const float* row = u_e + b * N;
        __shared__ float red[256];
        float m = -INFINITY;
        for (int n = tid; n < N; n += 256) m = fmaxf(m, row[n]);
        red[tid] = m;
        __syncthreads();
        for (int o = 128; o > 0; o >>= 1) {
            if (tid < o) red[tid] = fmaxf(red[tid], red[tid + o]);
            __syncthreads();
        }
        m = red[0];
        __syncthreads();
        float sum = 0.f;
        for (int n = tid; n < N; n += 256) sum += expf(row[n] - m);
        red[tid] = sum;
        __syncthreads();
        for (int o = 128; o > 0; o >>= 1) {
            if (tid < o) red[tid] += red[tid + o];
            __syncthreads();
        }
        const float lse = m + logf(red[0]);
        for (int n = tid; n < N; n += 256) ws_le[b * N + n] = row[n] - lse;
    } else if (b < 36) {
        // ---- chain log-softmax, transposed store ----
        const int n = (b - 16) * 256 + tid;
        if (n < N) {
            float v[C];
            float m = -INFINITY;
            for (int c = 0; c < C; ++c) {
                v[c] = u_cw[n * C + c];
                m = fmaxf(m, v[c]);
            }
            float s = 0.f;
            for (int c = 0; c < C; ++c) s += expf(v[c] - m);
            const float lse = m + logf(s);
            for (int c = 0; c < C; ++c) ws_lcwT[c * N + n] = v[c] - lse;
        }
    } else {
        // ---- HMM forward recursion, linear space, single wave ----
        if (tid < S) {
            const int j = tid;
            // log-softmax of state init
            float m = -INFINITY;
            for (int i = 0; i < S; ++i) m = fmaxf(m, u_init[i]);
            float ssum = 0.f;
            for (int i = 0; i < S; ++i) ssum += expf(u_init[i] - m);
            const float lse0 = m + logf(ssum);
            const float h0 = u_init[j] - lse0;
            out_h[j] = h0;
            ws_h[j] = h0;
            // row-softmax of transition: thread j computes lse of row j
            float mr = -INFINITY;
            for (int k = 0; k < S; ++k) mr = fmaxf(mr, u_T[j * S + k]);
            float sr = 0.f;
            for (int k = 0; k < S; ++k) sr += expf(u_T[j * S + k] - mr);
            const float lse_row = mr + logf(sr);
            // thread j holds column j of Texp: Texp[i][j] = exp(u_T[i][j] - lse_i)
            float texp[S];
            #pragma unroll
            for (int i = 0; i < S; ++i) {
                const float lse_i = __shfl(lse_row, i, 64);
                texp[i] = expf(u_T[i * S + j] - lse_i);
            }
            // p_{t+1}[j] = sum_i p_t[i] * Texp[i][j]; h_t = log(p_t)
            float p = expf(h0);
            for (int t = 1; t < T; ++t) {
                float pn = 0.f;
                #pragma unroll
                for (int i = 0; i < S; ++i) {
                    pn = fmaf(__shfl(p, i, 64), texp[i], pn);
                }
                p = pn;
                const float hv = logf(p);
                out_h[t * S + j] = hv;
                ws_h[t * S + j] = hv;
            }
        }
    }
}

// ---------------- Main fused kernel ----------------
// grid (S+1, T).
// bx < 16 : block (s=bx, t) writes the CONTIGUOUS 160 KB slab out_perm[t][s][:][:]
//           in linear address order (c outer, n inner):
//             out_perm[t][s][c][n] = le[s][n] + h[t][s] + lcwT[c][n]
// bx == 16: logsumexp over s for row t:
//             out0[t][n] = log(sum_s exp(le[s][n] + h[t][s]))
//           (exact without max subtraction: all terms <= 0, |a| ~< 25, no overflow
//            possible and exp stays in normal range)
//
// MEASURED (round-4 double-launch ablation): one main_kernel dispatch = 48.2 us
// marginal = 258 MB / 48 us = 5.4 TB/s, vs 6.5 TB/s harness-fill ceiling (40 us).
// The kernel is at the streaming-write roofline; the remaining ~230 us of dur_us
// is harness poison-fill (~157 us, 1.03 GB) + reset memsets/launch overhead.
__global__ __launch_bounds__(256) void main_kernel(const float* __restrict__ ws_le,
                                                   const float* __restrict__ ws_lcwT,
                                                   const float* __restrict__ ws_h,
                                                   float* __restrict__ out0,
                                                   float* __restrict__ out_perm) {
    const int t = blockIdx.y;
    const int bx = blockIdx.x;
    const int tid = threadIdx.x;

    if (bx < S) {
        const int s = bx;
        const float hs = ws_h[t * S + s];   // wave-uniform scalar load
        const f32x4* __restrict__ le4 = (const f32x4*)ws_le + s * N4;
        const f32x4* __restrict__ lc4 = (const f32x4*)ws_lcwT;
        f32x4* __restrict__ out4 = (f32x4*)out_perm + (size_t)(t * S + s) * (C * N4);

        for (int c = 0; c < C; ++c) {
            for (int base = 0; base < N4; base += 256) {
                const int n4 = base + tid;
                if (n4 < N4) {
                    const f32x4 e = le4[n4];
                    const f32x4 w = lc4[c * N4 + n4];
                    f32x4 r;
                    r.x = e.x + hs + w.x;
                    r.y = e.y + hs + w.y;
                    r.z = e.z + hs + w.z;
                    r.w = e.w + hs + w.w;
                    out4[c * N4 + n4] = r;
                }
            }
        }
    } else {
        __shared__ float h[S];
        if (tid < S) h[tid] = ws_h[t * S + tid];
        __syncthreads();
        const f32x4* __restrict__ le4 = (const f32x4*)ws_le;
        for (int base = 0; base < N4; base += 256) {
            const int n4 = base + tid;
            if (n4 < N4) {
                float sx = 0.f, sy = 0.f, sz = 0.f, sw = 0.f;
                #pragma unroll
                for (int s = 0; s < S; ++s) {
                    const f32x4 e = le4[s * N4 + n4];
                    const float hv = h[s];
                    sx += expf(e.x + hv);
                    sy += expf(e.y + hv);
                    sz += expf(e.z + hv);
                    sw += expf(e.w + hv);
                }
                f32x4 r;
                r.x = logf(sx);
                r.y = logf(sy);
                r.z = logf(sz);
                r.w = logf(sw);
                ((f32x4*)out0)[(size_t)t * N4 + n4] = r;
            }
        }
    }
}

extern "C" void kernel_launch(void* const* d_in, const int* in_sizes, int n_in,
                              void* d_out, int out_size, void* d_ws, size_t ws_size,
                              hipStream_t stream) {
    const float* u_init = (const float*)d_in[0];   // (S,)
    const float* u_cw   = (const float*)d_in[1];   // (1,N,C)
    const float* u_e    = (const float*)d_in[2];   // (S,N)
    const float* u_T    = (const float*)d_in[3];   // (S,S)

    float* out = (float*)d_out;
    float* out0     = out;                                          // (T,N)
    float* out_perm = out + (size_t)T * N;                          // (T,S,C,N)
    float* out_h    = out + (size_t)T * N + (size_t)T * S * C * N;  // (T,S)

    float* ws  = (float*)d_ws;
    float* ws_h    = ws;                   // 1600 floats
    float* ws_le   = ws + 1600;            // 80000 floats (offset 6400 B, 16B-aligned)
    float* ws_lcwT = ws + 1600 + 80000;    // 40000 floats (C,N transposed)

    prep_kernel<<<37, 256, 0, stream>>>(u_init, u_cw, u_e, u_T, ws_le, ws_lcwT, ws_h, out_h);
    main_kernel<<<dim3(S + 1, T), 256, 0, stream>>>(ws_le, ws_lcwT, ws_h, out0, out_perm);
}